// Round 7
// baseline (193.958 us; speedup 1.0000x reference)
//
#include <hip/hip_runtime.h>
#include <hip/hip_fp16.h>
#include <cstdint>
#include <cstddef>

constexpr int R  = 512;
constexpr int C  = 16;
constexpr int HW = R * R;
constexpr int NBINS = 512;    // 3 bits/axis, 3D Morton
constexpr int NPART = 8;      // XCD partitions (blockIdx & 7 heuristic)
constexpr int NCNT  = NBINS * NPART;
constexpr int CHUNK = 4096;   // points per block in hist/scatter (16/thread)

typedef float v4f __attribute__((ext_vector_type(4)));
typedef int   v4i __attribute__((ext_vector_type(4)));

// ---------------------------------------------------------------------------
// Transpose (C,H,W) fp32 -> (H,W,C) fp16.
// ---------------------------------------------------------------------------
__global__ __launch_bounds__(256) void transpose_chw_hwc_h(
    const float* __restrict__ p0, const float* __restrict__ p1,
    const float* __restrict__ p2, __half* __restrict__ dst)
{
    __shared__ float lds[64 * 17];
    const int y  = blockIdx.x;
    const int x0 = blockIdx.y * 64;
    const int pl = blockIdx.z;
    const float* src = (pl == 0) ? p0 : ((pl == 1) ? p1 : p2);
    const int tid = threadIdx.x;
    const int xl  = tid & 63;
    const int c0  = tid >> 6;
#pragma unroll
    for (int i = 0; i < 4; ++i) {
        const int c = c0 * 4 + i;
        lds[xl * 17 + c] = src[c * HW + y * R + x0 + xl];
    }
    __syncthreads();
    __half2* dbase = (__half2*)(dst + ((size_t)pl * HW + (size_t)(y * R + x0)) * C);
#pragma unroll
    for (int i = 0; i < 2; ++i) {
        const int j  = tid + i * 256;
        const int e0 = 2 * j;
        const float a = lds[(e0 >> 4) * 17 + (e0 & 15)];
        const float b = lds[(e0 >> 4) * 17 + ((e0 & 15) + 1)];
        dbase[j] = __floats2half2_rn(a, b);
    }
}

// 9-bit Morton key: 3 bits per axis (cells of 64px).
__device__ __forceinline__ uint32_t morton_key9(float xv0, float xv1, float xv2)
{
    const float s = 0.5f * (float)(R - 1);
    int c0 = (int)((xv0 + 1.0f) * s); c0 = min(max(c0, 0), R - 1); c0 >>= 6;
    int c1 = (int)((xv1 + 1.0f) * s); c1 = min(max(c1, 0), R - 1); c1 >>= 6;
    int c2 = (int)((xv2 + 1.0f) * s); c2 = min(max(c2, 0), R - 1); c2 >>= 6;
    uint32_t k = 0;
#pragma unroll
    for (int i = 0; i < 3; ++i) {
        k |= ((uint32_t)((c0 >> i) & 1)) << (3 * i + 2);
        k |= ((uint32_t)((c1 >> i) & 1)) << (3 * i + 1);
        k |= ((uint32_t)((c2 >> i) & 1)) << (3 * i + 0);
    }
    return k;
}

// ---------------------------------------------------------------------------
// Histogram with LDS aggregation: <=512 global atomics per 4096 points.
// ---------------------------------------------------------------------------
__global__ __launch_bounds__(256) void hist_pts(
    const float* __restrict__ x, unsigned int* __restrict__ counts, int B)
{
    __shared__ unsigned int h[NBINS];
    const int tid = threadIdx.x;
    for (int i = tid; i < NBINS; i += 256) h[i] = 0;
    __syncthreads();
    const int start = blockIdx.x * CHUNK;
#pragma unroll
    for (int j = 0; j < CHUNK / 256; ++j) {
        const int i = start + j * 256 + tid;
        if (i < B) {
            const float a = x[(size_t)i * 3 + 0];
            const float b = x[(size_t)i * 3 + 1];
            const float c = x[(size_t)i * 3 + 2];
            atomicAdd(&h[morton_key9(a, b, c)], 1u);
        }
    }
    __syncthreads();
    unsigned int* cb = counts + (blockIdx.x & (NPART - 1)) * NBINS;
    for (int i = tid; i < NBINS; i += 256) {
        const unsigned int c = h[i];
        if (c) atomicAdd(&cb[i], c);
    }
}

// Exclusive scan over 4096 counters in LOGICAL order (key,part): records are
// BIN-MAJOR (Morton octant j = contiguous ~1/8 slice for sampler-XCD j),
// counters stay part-major in memory for XCD-local atomics.
__global__ __launch_bounds__(1024) void scan_counts(
    const unsigned int* __restrict__ counts, unsigned int* __restrict__ cursor)
{
    __shared__ unsigned int s[1024];
    const int t = threadIdx.x;
    unsigned int v[4];
    unsigned int sum = 0;
#pragma unroll
    for (int i = 0; i < 4; ++i) {
        const int L = t * 4 + i;            // logical = key*NPART + part
        const int key = L >> 3, part = L & 7;
        v[i] = counts[part * NBINS + key];
        sum += v[i];
    }
    unsigned int run = 0;
#pragma unroll
    for (int i = 0; i < 4; ++i) { const unsigned int tmp = v[i]; v[i] = run; run += tmp; }
    s[t] = sum;
    __syncthreads();
    unsigned int incl = sum;
    for (int off = 1; off < 1024; off <<= 1) {
        const unsigned int u = (t >= off) ? s[t - off] : 0u;
        __syncthreads();
        incl += u;
        s[t] = incl;
        __syncthreads();
    }
    const unsigned int excl = incl - sum;
#pragma unroll
    for (int i = 0; i < 4; ++i) {
        const int L = t * 4 + i;
        const int key = L >> 3, part = L & 7;
        cursor[part * NBINS + key] = excl + v[i];
    }
}

// ---------------------------------------------------------------------------
// Scatter with block-local counting sort (bin-sorted, run-coalesced writes).
// ---------------------------------------------------------------------------
__global__ __launch_bounds__(256) void scatter_pts(
    const float* __restrict__ x, unsigned int* __restrict__ cursor,
    int4* __restrict__ recs, int B)
{
    __shared__ unsigned int h[NBINS];
    __shared__ unsigned int gbase[NBINS];
    __shared__ unsigned int lpre[NBINS];
    __shared__ unsigned int lcur[NBINS];
    __shared__ int4 buf[CHUNK];
    __shared__ unsigned short binOf[CHUNK];

    const int tid   = threadIdx.x;
    const int start = blockIdx.x * CHUNK;
    const int V     = min(CHUNK, B - start);

    for (int i = tid; i < NBINS; i += 256) h[i] = 0;
    __syncthreads();

    float pa[CHUNK / 256], pb_[CHUNK / 256], pc[CHUNK / 256];
    unsigned int pk[CHUNK / 256];
#pragma unroll
    for (int j = 0; j < CHUNK / 256; ++j) {
        const int i = start + j * 256 + tid;
        pk[j] = 0xFFFFFFFFu;
        if (i < B) {
            pa[j] = x[(size_t)i * 3 + 0];
            pb_[j] = x[(size_t)i * 3 + 1];
            pc[j] = x[(size_t)i * 3 + 2];
            pk[j] = morton_key9(pa[j], pb_[j], pc[j]);
            atomicAdd(&h[pk[j]], 1u);
        }
    }
    __syncthreads();

    unsigned int* cb = cursor + (blockIdx.x & (NPART - 1)) * NBINS;
    for (int b = tid; b < NBINS; b += 256) {
        const unsigned int c = h[b];
        gbase[b] = c ? atomicAdd(&cb[b], c) : 0u;
    }
    if (tid < 64) {
        unsigned int loc[8];
        unsigned int tot = 0;
#pragma unroll
        for (int j = 0; j < 8; ++j) { loc[j] = h[tid * 8 + j]; tot += loc[j]; }
        unsigned int run = tot;
#pragma unroll
        for (int d = 1; d < 64; d <<= 1) {
            const unsigned int u = __shfl_up(run, (unsigned)d, 64);
            if (tid >= d) run += u;
        }
        unsigned int excl = run - tot;
#pragma unroll
        for (int j = 0; j < 8; ++j) { lpre[tid * 8 + j] = excl; excl += loc[j]; }
    }
    __syncthreads();
    for (int b = tid; b < NBINS; b += 256) lcur[b] = lpre[b];
    __syncthreads();

#pragma unroll
    for (int j = 0; j < CHUNK / 256; ++j) {
        if (pk[j] != 0xFFFFFFFFu) {
            const int i = start + j * 256 + tid;
            const unsigned int rk = atomicAdd(&lcur[pk[j]], 1u);
            buf[rk] = make_int4(__float_as_int(pa[j]), __float_as_int(pb_[j]),
                                __float_as_int(pc[j]), i);
            binOf[rk] = (unsigned short)pk[j];
        }
    }
    __syncthreads();

    for (int idx = tid; idx < V; idx += 256) {
        const int4 rc = buf[idx];
        const int  k  = binOf[idx];
        const unsigned int dest = gbase[k] + ((unsigned int)idx - lpre[k]);
        const v4i rv = { rc.x, rc.y, rc.z, rc.w };
        __builtin_nontemporal_store(rv, (v4i*)&recs[dest]);
    }
}

// ---------------------------------------------------------------------------
// Sampler. __launch_bounds__(256, 3) caps ~170 VGPR (12 waves/CU) so the full
// 24-load hoist survives register allocation (round-6 compiler chose 48 VGPR
// and serialized to MLP~4). Consume order is software-pipelined: plane-0
// weights/accumulate run while plane-1/2 loads are still in flight.
// ---------------------------------------------------------------------------
__global__ __launch_bounds__(256, 3) void sample_sorted(
    const int4* __restrict__ recs, const __half* __restrict__ t,
    float* __restrict__ out, int B, int q, int r)
{
    const uint32_t bid  = blockIdx.x;
    const uint32_t xcd  = bid & 7u;
    const uint32_t slot = bid >> 3;
    const uint32_t base = (xcd < (uint32_t)r) ? xcd * (q + 1)
                                              : (uint32_t)r * (q + 1) + (xcd - r) * q;
    const uint32_t lb   = base + slot;

    const int tid = (int)(lb * 256u + threadIdx.x);
    const int pr  = tid >> 1;
    const int h   = tid & 1;
    const int p0  = pr * 2;
    if (p0 >= B) return;
    const int p1m = min(p0 + 1, B - 1);

    v4i rec[2];
    rec[0] = __builtin_nontemporal_load((const v4i*)&recs[p0]);
    rec[1] = __builtin_nontemporal_load((const v4i*)&recs[p1m]);

    // ---- address + weight computation for all 2x3 plane-samples ----
    float wx_[2][3], wy_[2][3];
    const __half* addr[2][3][4];
#pragma unroll
    for (int e = 0; e < 2; ++e) {
        const float xv0 = __int_as_float(rec[e].x);
        const float xv1 = __int_as_float(rec[e].y);
        const float xv2 = __int_as_float(rec[e].z);
#pragma unroll
        for (int pl = 0; pl < 3; ++pl) {
            const float gx = (pl == 2) ? xv1 : xv0;
            const float gy = (pl == 0) ? xv1 : xv2;
            const float px = (gx + 1.0f) * 0.5f * (float)(R - 1);
            const float py = (gy + 1.0f) * 0.5f * (float)(R - 1);
            const float x0f = floorf(px), y0f = floorf(py);
            wx_[e][pl] = px - x0f;
            wy_[e][pl] = py - y0f;
            int x0 = (int)x0f; x0 = min(max(x0, 0), R - 1);
            int y0 = (int)y0f; y0 = min(max(y0, 0), R - 1);
            const int x1 = min(x0 + 1, R - 1);
            const int y1 = min(y0 + 1, R - 1);
            const __half* pb = t + (size_t)pl * (size_t)(HW * C) + h * 8;
            addr[e][pl][0] = pb + (size_t)(y0 * R + x0) * C;
            addr[e][pl][1] = pb + (size_t)(y0 * R + x1) * C;
            addr[e][pl][2] = pb + (size_t)(y1 * R + x0) * C;
            addr[e][pl][3] = pb + (size_t)(y1 * R + x1) * C;
        }
    }

    // ---- issue ALL 24 corner loads (static indices -> registers) ----
    int4 raw[2][3][4];
#pragma unroll
    for (int pl = 0; pl < 3; ++pl)
#pragma unroll
        for (int c2 = 0; c2 < 4; ++c2) {
            raw[0][pl][c2] = *(const int4*)addr[0][pl][c2];
            raw[1][pl][c2] = *(const int4*)addr[1][pl][c2];
        }

    // ---- consume: per-plane weights & accumulate ----
    float acc[2][8];
#pragma unroll
    for (int e = 0; e < 2; ++e)
#pragma unroll
        for (int k = 0; k < 8; ++k) acc[e][k] = 1.f;

#pragma unroll
    for (int pl = 0; pl < 3; ++pl)
#pragma unroll
    for (int e = 0; e < 2; ++e) {
        const float wx = wx_[e][pl], wy = wy_[e][pl];
        const float w00 = (1.f - wx) * (1.f - wy);
        const float w01 = wx * (1.f - wy);
        const float w10 = (1.f - wx) * wy;
        const float w11 = wx * wy;
        const __half2* f00 = (const __half2*)&raw[e][pl][0];
        const __half2* f01 = (const __half2*)&raw[e][pl][1];
        const __half2* f10 = (const __half2*)&raw[e][pl][2];
        const __half2* f11 = (const __half2*)&raw[e][pl][3];
#pragma unroll
        for (int i2 = 0; i2 < 4; ++i2) {
            const float2 a0 = __half22float2(f00[i2]);
            const float2 a1 = __half22float2(f01[i2]);
            const float2 a2 = __half22float2(f10[i2]);
            const float2 a3 = __half22float2(f11[i2]);
            acc[e][2 * i2 + 0] *= a0.x * w00 + a1.x * w01 + a2.x * w10 + a3.x * w11;
            acc[e][2 * i2 + 1] *= a0.y * w00 + a1.y * w01 + a2.y * w10 + a3.y * w11;
        }
    }

#pragma unroll
    for (int e = 0; e < 2; ++e) {
        if (e == 0 || p0 + 1 < B) {
            float* o = out + (size_t)rec[e].w * C + h * 8;
            const v4f o0 = { acc[e][0], acc[e][1], acc[e][2], acc[e][3] };
            const v4f o1 = { acc[e][4], acc[e][5], acc[e][6], acc[e][7] };
            __builtin_nontemporal_store(o0, (v4f*)(o + 0));
            __builtin_nontemporal_store(o1, (v4f*)(o + 4));
        }
    }
}

// ============================ fallback paths ================================
__global__ __launch_bounds__(256) void transpose_chw_hwc(
    const float* __restrict__ p0, const float* __restrict__ p1,
    const float* __restrict__ p2, float* __restrict__ dst)
{
    __shared__ float lds[64 * 17];
    const int y  = blockIdx.x;
    const int x0 = blockIdx.y * 64;
    const int pl = blockIdx.z;
    const float* src = (pl == 0) ? p0 : ((pl == 1) ? p1 : p2);
    const int tid = threadIdx.x;
    const int xl  = tid & 63;
    const int c0  = tid >> 6;
#pragma unroll
    for (int i = 0; i < 4; ++i) {
        const int c = c0 * 4 + i;
        lds[xl * 17 + c] = src[c * HW + y * R + x0 + xl];
    }
    __syncthreads();
    float* dbase = dst + ((size_t)pl * HW + (size_t)(y * R + x0)) * C;
#pragma unroll
    for (int i = 0; i < 4; ++i) {
        const int j = tid + i * 256;
        dbase[j] = lds[(j >> 4) * 17 + (j & 15)];
    }
}

__global__ __launch_bounds__(256) void sample_hwc(
    const float* __restrict__ x, const float* __restrict__ t,
    float* __restrict__ out, int B)
{
    const int tid = blockIdx.x * 256 + threadIdx.x;
    const int p   = tid >> 2;
    const int cg  = tid & 3;
    if (p >= B) return;

    const float xv0 = x[(size_t)p * 3 + 0];
    const float xv1 = x[(size_t)p * 3 + 1];
    const float xv2 = x[(size_t)p * 3 + 2];
    const float gxs[3] = { xv0, xv0, xv1 };
    const float gys[3] = { xv1, xv2, xv2 };
    float4 acc = make_float4(1.f, 1.f, 1.f, 1.f);

#pragma unroll
    for (int pl = 0; pl < 3; ++pl) {
        const float gx = gxs[pl], gy = gys[pl];
        const float px = (gx + 1.0f) * 0.5f * (float)(R - 1);
        const float py = (gy + 1.0f) * 0.5f * (float)(R - 1);
        const float x0f = floorf(px), y0f = floorf(py);
        const float wx = px - x0f,   wy = py - y0f;
        int x0 = (int)x0f; x0 = min(max(x0, 0), R - 1);
        int y0 = (int)y0f; y0 = min(max(y0, 0), R - 1);
        const int x1 = min(x0 + 1, R - 1);
        const int y1 = min(y0 + 1, R - 1);

        const float* pb = t + (size_t)pl * (size_t)(HW * C) + cg * 4;
        const float4 p00 = *(const float4*)(pb + (size_t)(y0 * R + x0) * C);
        const float4 p01 = *(const float4*)(pb + (size_t)(y0 * R + x1) * C);
        const float4 p10 = *(const float4*)(pb + (size_t)(y1 * R + x0) * C);
        const float4 p11 = *(const float4*)(pb + (size_t)(y1 * R + x1) * C);

        const float w00 = (1.f - wx) * (1.f - wy);
        const float w01 = wx * (1.f - wy);
        const float w10 = (1.f - wx) * wy;
        const float w11 = wx * wy;

        float4 f;
        f.x = p00.x * w00 + p01.x * w01 + p10.x * w10 + p11.x * w11;
        f.y = p00.y * w00 + p01.y * w01 + p10.y * w10 + p11.y * w11;
        f.z = p00.z * w00 + p01.z * w01 + p10.z * w10 + p11.z * w11;
        f.w = p00.w * w00 + p01.w * w01 + p10.w * w10 + p11.w * w11;

        acc.x *= f.x; acc.y *= f.y; acc.z *= f.z; acc.w *= f.w;
    }

    *(float4*)(out + (size_t)p * C + cg * 4) = acc;
}

__global__ __launch_bounds__(256) void sample_chw(
    const float* __restrict__ x,
    const float* __restrict__ p0, const float* __restrict__ p1,
    const float* __restrict__ p2, float* __restrict__ out, int B)
{
    const int tid = blockIdx.x * 256 + threadIdx.x;
    const int p   = tid >> 2;
    const int cg  = tid & 3;
    if (p >= B) return;
    const float xv0 = x[(size_t)p * 3 + 0];
    const float xv1 = x[(size_t)p * 3 + 1];
    const float xv2 = x[(size_t)p * 3 + 2];
    const float gxs[3] = { xv0, xv0, xv1 };
    const float gys[3] = { xv1, xv2, xv2 };
    const float* planes[3] = { p0, p1, p2 };
    float acc[4] = {1.f, 1.f, 1.f, 1.f};
#pragma unroll
    for (int pl = 0; pl < 3; ++pl) {
        const float gx = gxs[pl], gy = gys[pl];
        const float px = (gx + 1.0f) * 0.5f * (float)(R - 1);
        const float py = (gy + 1.0f) * 0.5f * (float)(R - 1);
        const float x0f = floorf(px), y0f = floorf(py);
        const float wx = px - x0f,   wy = py - y0f;
        int x0 = (int)x0f; x0 = min(max(x0, 0), R - 1);
        int y0 = (int)y0f; y0 = min(max(y0, 0), R - 1);
        const int x1 = min(x0 + 1, R - 1);
        const int y1 = min(y0 + 1, R - 1);
        const float w00 = (1.f - wx) * (1.f - wy);
        const float w01 = wx * (1.f - wy);
        const float w10 = (1.f - wx) * wy;
        const float w11 = wx * wy;
        const float* pb = planes[pl];
#pragma unroll
        for (int k = 0; k < 4; ++k) {
            const int c = cg * 4 + k;
            const float* b2 = pb + (size_t)c * HW;
            const float v00 = b2[y0 * R + x0];
            const float v01 = b2[y0 * R + x1];
            const float v10 = b2[y1 * R + x0];
            const float v11 = b2[y1 * R + x1];
            acc[k] *= v00 * w00 + v01 * w01 + v10 * w10 + v11 * w11;
        }
    }
    float* o = out + (size_t)p * C + cg * 4;
    o[0] = acc[0]; o[1] = acc[1]; o[2] = acc[2]; o[3] = acc[3];
}

// ===========================================================================
extern "C" void kernel_launch(void* const* d_in, const int* in_sizes, int n_in,
                              void* d_out, int out_size, void* d_ws, size_t ws_size,
                              hipStream_t stream) {
    const float* x  = (const float*)d_in[0];
    const float* p0 = (const float*)d_in[1];
    const float* p1 = (const float*)d_in[2];
    const float* p2 = (const float*)d_in[3];
    float* out = (float*)d_out;
    const int B = in_sizes[0] / 3;

    const size_t t_bytes    = (size_t)3 * HW * C * sizeof(__half);     // 24 MiB
    const size_t recs_bytes = (size_t)B * 16;                          // 32 MB
    const size_t cnt_bytes  = (size_t)NCNT * 4;                        // 16 KiB
    const size_t off_t      = 0;
    const size_t off_recs   = (t_bytes + 255) & ~(size_t)255;
    const size_t off_counts = (off_recs + recs_bytes + 255) & ~(size_t)255;
    const size_t off_cursor = (off_counts + cnt_bytes + 255) & ~(size_t)255;
    const size_t need_full  = off_cursor + cnt_bytes;

    const size_t need_fp32  = (size_t)3 * HW * C * sizeof(float);      // 48 MiB

    if (d_ws != nullptr && ws_size >= need_full) {
        __half*       t      = (__half*)((char*)d_ws + off_t);
        int4*         recs   = (int4*)((char*)d_ws + off_recs);
        unsigned int* counts = (unsigned int*)((char*)d_ws + off_counts);
        unsigned int* cursor = (unsigned int*)((char*)d_ws + off_cursor);

        dim3 tg(R, R / 64, 3);
        transpose_chw_hwc_h<<<tg, 256, 0, stream>>>(p0, p1, p2, t);

        hipMemsetAsync(counts, 0, cnt_bytes, stream);
        const int nblkP = (B + CHUNK - 1) / CHUNK;
        hist_pts<<<nblkP, 256, 0, stream>>>(x, counts, B);
        scan_counts<<<1, 1024, 0, stream>>>(counts, cursor);
        scatter_pts<<<nblkP, 256, 0, stream>>>(x, cursor, recs, B);

        const int nthr2 = B;                       // 2 lanes/pt, 2 pts/thread
        const int nblk2 = (nthr2 + 255) / 256;
        const int q = nblk2 / 8, r = nblk2 % 8;
        sample_sorted<<<nblk2, 256, 0, stream>>>(recs, t, out, B, q, r);
    } else if (d_ws != nullptr && ws_size >= need_fp32) {
        float* t = (float*)d_ws;
        dim3 tg(R, R / 64, 3);
        transpose_chw_hwc<<<tg, 256, 0, stream>>>(p0, p1, p2, t);
        const int nthr = B * 4;
        const int nblk = (nthr + 255) / 256;
        sample_hwc<<<nblk, 256, 0, stream>>>(x, t, out, B);
    } else {
        const int nthr = B * 4;
        const int nblk = (nthr + 255) / 256;
        sample_chw<<<nblk, 256, 0, stream>>>(x, p0, p1, p2, out, B);
    }
}

// Round 8
// 172.226 us; speedup vs baseline: 1.1262x; 1.1262x over previous
//
#include <hip/hip_runtime.h>
#include <hip/hip_fp16.h>
#include <cstdint>
#include <cstddef>

constexpr int R  = 512;
constexpr int C  = 16;
constexpr int HW = R * R;
constexpr int NBINS = 512;    // 3 bits/axis, 3D Morton
constexpr int NPART = 8;      // XCD partitions (blockIdx & 7 heuristic)
constexpr int NCNT  = NBINS * NPART;
constexpr int CHUNK = 4096;   // points per block in hist/scatter (16/thread)

typedef float v4f __attribute__((ext_vector_type(4)));
typedef int   v4i __attribute__((ext_vector_type(4)));

// ---------------------------------------------------------------------------
// Transpose (C,H,W) fp32 -> (H,W,C) fp16.
// ---------------------------------------------------------------------------
__global__ __launch_bounds__(256) void transpose_chw_hwc_h(
    const float* __restrict__ p0, const float* __restrict__ p1,
    const float* __restrict__ p2, __half* __restrict__ dst)
{
    __shared__ float lds[64 * 17];
    const int y  = blockIdx.x;
    const int x0 = blockIdx.y * 64;
    const int pl = blockIdx.z;
    const float* src = (pl == 0) ? p0 : ((pl == 1) ? p1 : p2);
    const int tid = threadIdx.x;
    const int xl  = tid & 63;
    const int c0  = tid >> 6;
#pragma unroll
    for (int i = 0; i < 4; ++i) {
        const int c = c0 * 4 + i;
        lds[xl * 17 + c] = src[c * HW + y * R + x0 + xl];
    }
    __syncthreads();
    __half2* dbase = (__half2*)(dst + ((size_t)pl * HW + (size_t)(y * R + x0)) * C);
#pragma unroll
    for (int i = 0; i < 2; ++i) {
        const int j  = tid + i * 256;
        const int e0 = 2 * j;
        const float a = lds[(e0 >> 4) * 17 + (e0 & 15)];
        const float b = lds[(e0 >> 4) * 17 + ((e0 & 15) + 1)];
        dbase[j] = __floats2half2_rn(a, b);
    }
}

// 9-bit Morton key: 3 bits per axis (cells of 64px).
__device__ __forceinline__ uint32_t morton_key9(float xv0, float xv1, float xv2)
{
    const float s = 0.5f * (float)(R - 1);
    int c0 = (int)((xv0 + 1.0f) * s); c0 = min(max(c0, 0), R - 1); c0 >>= 6;
    int c1 = (int)((xv1 + 1.0f) * s); c1 = min(max(c1, 0), R - 1); c1 >>= 6;
    int c2 = (int)((xv2 + 1.0f) * s); c2 = min(max(c2, 0), R - 1); c2 >>= 6;
    uint32_t k = 0;
#pragma unroll
    for (int i = 0; i < 3; ++i) {
        k |= ((uint32_t)((c0 >> i) & 1)) << (3 * i + 2);
        k |= ((uint32_t)((c1 >> i) & 1)) << (3 * i + 1);
        k |= ((uint32_t)((c2 >> i) & 1)) << (3 * i + 0);
    }
    return k;
}

// ---------------------------------------------------------------------------
// Histogram with LDS aggregation: <=512 global atomics per 4096 points.
// ---------------------------------------------------------------------------
__global__ __launch_bounds__(256) void hist_pts(
    const float* __restrict__ x, unsigned int* __restrict__ counts, int B)
{
    __shared__ unsigned int h[NBINS];
    const int tid = threadIdx.x;
    for (int i = tid; i < NBINS; i += 256) h[i] = 0;
    __syncthreads();
    const int start = blockIdx.x * CHUNK;
#pragma unroll
    for (int j = 0; j < CHUNK / 256; ++j) {
        const int i = start + j * 256 + tid;
        if (i < B) {
            const float a = x[(size_t)i * 3 + 0];
            const float b = x[(size_t)i * 3 + 1];
            const float c = x[(size_t)i * 3 + 2];
            atomicAdd(&h[morton_key9(a, b, c)], 1u);
        }
    }
    __syncthreads();
    unsigned int* cb = counts + (blockIdx.x & (NPART - 1)) * NBINS;
    for (int i = tid; i < NBINS; i += 256) {
        const unsigned int c = h[i];
        if (c) atomicAdd(&cb[i], c);
    }
}

// Exclusive scan over 4096 counters in LOGICAL order (key,part): records are
// BIN-MAJOR (Morton octant j = contiguous ~1/8 slice for sampler-XCD j),
// counters stay part-major in memory for XCD-local atomics.
__global__ __launch_bounds__(1024) void scan_counts(
    const unsigned int* __restrict__ counts, unsigned int* __restrict__ cursor)
{
    __shared__ unsigned int s[1024];
    const int t = threadIdx.x;
    unsigned int v[4];
    unsigned int sum = 0;
#pragma unroll
    for (int i = 0; i < 4; ++i) {
        const int L = t * 4 + i;            // logical = key*NPART + part
        const int key = L >> 3, part = L & 7;
        v[i] = counts[part * NBINS + key];
        sum += v[i];
    }
    unsigned int run = 0;
#pragma unroll
    for (int i = 0; i < 4; ++i) { const unsigned int tmp = v[i]; v[i] = run; run += tmp; }
    s[t] = sum;
    __syncthreads();
    unsigned int incl = sum;
    for (int off = 1; off < 1024; off <<= 1) {
        const unsigned int u = (t >= off) ? s[t - off] : 0u;
        __syncthreads();
        incl += u;
        s[t] = incl;
        __syncthreads();
    }
    const unsigned int excl = incl - sum;
#pragma unroll
    for (int i = 0; i < 4; ++i) {
        const int L = t * 4 + i;
        const int key = L >> 3, part = L & 7;
        cursor[part * NBINS + key] = excl + v[i];
    }
}

// ---------------------------------------------------------------------------
// Scatter with block-local counting sort (bin-sorted, run-coalesced writes).
// ---------------------------------------------------------------------------
__global__ __launch_bounds__(256) void scatter_pts(
    const float* __restrict__ x, unsigned int* __restrict__ cursor,
    int4* __restrict__ recs, int B)
{
    __shared__ unsigned int h[NBINS];
    __shared__ unsigned int gbase[NBINS];
    __shared__ unsigned int lpre[NBINS];
    __shared__ unsigned int lcur[NBINS];
    __shared__ int4 buf[CHUNK];
    __shared__ unsigned short binOf[CHUNK];

    const int tid   = threadIdx.x;
    const int start = blockIdx.x * CHUNK;
    const int V     = min(CHUNK, B - start);

    for (int i = tid; i < NBINS; i += 256) h[i] = 0;
    __syncthreads();

    float pa[CHUNK / 256], pb_[CHUNK / 256], pc[CHUNK / 256];
    unsigned int pk[CHUNK / 256];
#pragma unroll
    for (int j = 0; j < CHUNK / 256; ++j) {
        const int i = start + j * 256 + tid;
        pk[j] = 0xFFFFFFFFu;
        if (i < B) {
            pa[j] = x[(size_t)i * 3 + 0];
            pb_[j] = x[(size_t)i * 3 + 1];
            pc[j] = x[(size_t)i * 3 + 2];
            pk[j] = morton_key9(pa[j], pb_[j], pc[j]);
            atomicAdd(&h[pk[j]], 1u);
        }
    }
    __syncthreads();

    unsigned int* cb = cursor + (blockIdx.x & (NPART - 1)) * NBINS;
    for (int b = tid; b < NBINS; b += 256) {
        const unsigned int c = h[b];
        gbase[b] = c ? atomicAdd(&cb[b], c) : 0u;
    }
    if (tid < 64) {
        unsigned int loc[8];
        unsigned int tot = 0;
#pragma unroll
        for (int j = 0; j < 8; ++j) { loc[j] = h[tid * 8 + j]; tot += loc[j]; }
        unsigned int run = tot;
#pragma unroll
        for (int d = 1; d < 64; d <<= 1) {
            const unsigned int u = __shfl_up(run, (unsigned)d, 64);
            if (tid >= d) run += u;
        }
        unsigned int excl = run - tot;
#pragma unroll
        for (int j = 0; j < 8; ++j) { lpre[tid * 8 + j] = excl; excl += loc[j]; }
    }
    __syncthreads();
    for (int b = tid; b < NBINS; b += 256) lcur[b] = lpre[b];
    __syncthreads();

#pragma unroll
    for (int j = 0; j < CHUNK / 256; ++j) {
        if (pk[j] != 0xFFFFFFFFu) {
            const int i = start + j * 256 + tid;
            const unsigned int rk = atomicAdd(&lcur[pk[j]], 1u);
            buf[rk] = make_int4(__float_as_int(pa[j]), __float_as_int(pb_[j]),
                                __float_as_int(pc[j]), i);
            binOf[rk] = (unsigned short)pk[j];
        }
    }
    __syncthreads();

    for (int idx = tid; idx < V; idx += 256) {
        const int4 rc = buf[idx];
        const int  k  = binOf[idx];
        const unsigned int dest = gbase[k] + ((unsigned int)idx - lpre[k]);
        const v4i rv = { rc.x, rc.y, rc.z, rc.w };
        __builtin_nontemporal_store(rv, (v4i*)&recs[dest]);
    }
}

// ---------------------------------------------------------------------------
// Sampler. All 24 corner loads issued, then __builtin_amdgcn_sched_barrier(0)
// prevents the scheduler from sinking any load past it -> forced 24-deep MLP
// (rounds 6/7 showed the compiler otherwise interleaves load->use at ~4-deep,
// VGPR 48-56). Addresses are 32-bit byte offsets from the uniform base so the
// address cost is 1 VGPR per load (SADDR+voffset form), keeping peak pressure
// ~130 VGPR (~3-4 waves/SIMD).
// ---------------------------------------------------------------------------
__global__ __launch_bounds__(256) void sample_sorted(
    const int4* __restrict__ recs, const __half* __restrict__ t,
    float* __restrict__ out, int B, int q, int r)
{
    const uint32_t bid  = blockIdx.x;
    const uint32_t xcd  = bid & 7u;
    const uint32_t slot = bid >> 3;
    const uint32_t base = (xcd < (uint32_t)r) ? xcd * (q + 1)
                                              : (uint32_t)r * (q + 1) + (xcd - r) * q;
    const uint32_t lb   = base + slot;

    const int tid = (int)(lb * 256u + threadIdx.x);
    const int pr  = tid >> 1;
    const int h   = tid & 1;
    const int p0  = pr * 2;
    if (p0 >= B) return;
    const int p1m = min(p0 + 1, B - 1);

    v4i rec[2];
    rec[0] = __builtin_nontemporal_load((const v4i*)&recs[p0]);
    rec[1] = __builtin_nontemporal_load((const v4i*)&recs[p1m]);

    // ---- weights + 24 byte-offsets (32-bit, from uniform base) ----
    float wx_[2][3], wy_[2][3];
    uint32_t off[2][3][4];
    const char* tb = (const char*)t;
    const uint32_t hofs = (uint32_t)h * 16u;            // 8 halves = 16B
#pragma unroll
    for (int e = 0; e < 2; ++e) {
        const float xv0 = __int_as_float(rec[e].x);
        const float xv1 = __int_as_float(rec[e].y);
        const float xv2 = __int_as_float(rec[e].z);
#pragma unroll
        for (int pl = 0; pl < 3; ++pl) {
            const float gx = (pl == 2) ? xv1 : xv0;
            const float gy = (pl == 0) ? xv1 : xv2;
            const float px = (gx + 1.0f) * 0.5f * (float)(R - 1);
            const float py = (gy + 1.0f) * 0.5f * (float)(R - 1);
            const float x0f = floorf(px), y0f = floorf(py);
            wx_[e][pl] = px - x0f;
            wy_[e][pl] = py - y0f;
            int x0 = (int)x0f; x0 = min(max(x0, 0), R - 1);
            int y0 = (int)y0f; y0 = min(max(y0, 0), R - 1);
            const int x1 = min(x0 + 1, R - 1);
            const int y1 = min(y0 + 1, R - 1);
            const uint32_t pb = (uint32_t)pl * (uint32_t)(HW * C * 2) + hofs;
            const uint32_t r0 = (uint32_t)(y0 * R) * (C * 2);
            const uint32_t r1 = (uint32_t)(y1 * R) * (C * 2);
            const uint32_t cx0 = (uint32_t)x0 * (C * 2);
            const uint32_t cx1 = (uint32_t)x1 * (C * 2);
            off[e][pl][0] = pb + r0 + cx0;
            off[e][pl][1] = pb + r0 + cx1;
            off[e][pl][2] = pb + r1 + cx0;
            off[e][pl][3] = pb + r1 + cx1;
        }
    }

    // ---- issue ALL 24 loads; fence stops the scheduler from sinking them ----
    int4 raw[2][3][4];
#pragma unroll
    for (int pl = 0; pl < 3; ++pl)
#pragma unroll
        for (int c2 = 0; c2 < 4; ++c2) {
            raw[0][pl][c2] = *(const int4*)(tb + off[0][pl][c2]);
            raw[1][pl][c2] = *(const int4*)(tb + off[1][pl][c2]);
        }
    __builtin_amdgcn_sched_barrier(0);

    // ---- consume ----
    float acc[2][8];
#pragma unroll
    for (int e = 0; e < 2; ++e)
#pragma unroll
        for (int k = 0; k < 8; ++k) acc[e][k] = 1.f;

#pragma unroll
    for (int pl = 0; pl < 3; ++pl)
#pragma unroll
    for (int e = 0; e < 2; ++e) {
        const float wx = wx_[e][pl], wy = wy_[e][pl];
        const float w00 = (1.f - wx) * (1.f - wy);
        const float w01 = wx * (1.f - wy);
        const float w10 = (1.f - wx) * wy;
        const float w11 = wx * wy;
        const __half2* f00 = (const __half2*)&raw[e][pl][0];
        const __half2* f01 = (const __half2*)&raw[e][pl][1];
        const __half2* f10 = (const __half2*)&raw[e][pl][2];
        const __half2* f11 = (const __half2*)&raw[e][pl][3];
#pragma unroll
        for (int i2 = 0; i2 < 4; ++i2) {
            const float2 a0 = __half22float2(f00[i2]);
            const float2 a1 = __half22float2(f01[i2]);
            const float2 a2 = __half22float2(f10[i2]);
            const float2 a3 = __half22float2(f11[i2]);
            acc[e][2 * i2 + 0] *= a0.x * w00 + a1.x * w01 + a2.x * w10 + a3.x * w11;
            acc[e][2 * i2 + 1] *= a0.y * w00 + a1.y * w01 + a2.y * w10 + a3.y * w11;
        }
    }

#pragma unroll
    for (int e = 0; e < 2; ++e) {
        if (e == 0 || p0 + 1 < B) {
            float* o = out + (size_t)rec[e].w * C + h * 8;
            const v4f o0 = { acc[e][0], acc[e][1], acc[e][2], acc[e][3] };
            const v4f o1 = { acc[e][4], acc[e][5], acc[e][6], acc[e][7] };
            __builtin_nontemporal_store(o0, (v4f*)(o + 0));
            __builtin_nontemporal_store(o1, (v4f*)(o + 4));
        }
    }
}

// ============================ fallback paths ================================
__global__ __launch_bounds__(256) void transpose_chw_hwc(
    const float* __restrict__ p0, const float* __restrict__ p1,
    const float* __restrict__ p2, float* __restrict__ dst)
{
    __shared__ float lds[64 * 17];
    const int y  = blockIdx.x;
    const int x0 = blockIdx.y * 64;
    const int pl = blockIdx.z;
    const float* src = (pl == 0) ? p0 : ((pl == 1) ? p1 : p2);
    const int tid = threadIdx.x;
    const int xl  = tid & 63;
    const int c0  = tid >> 6;
#pragma unroll
    for (int i = 0; i < 4; ++i) {
        const int c = c0 * 4 + i;
        lds[xl * 17 + c] = src[c * HW + y * R + x0 + xl];
    }
    __syncthreads();
    float* dbase = dst + ((size_t)pl * HW + (size_t)(y * R + x0)) * C;
#pragma unroll
    for (int i = 0; i < 4; ++i) {
        const int j = tid + i * 256;
        dbase[j] = lds[(j >> 4) * 17 + (j & 15)];
    }
}

__global__ __launch_bounds__(256) void sample_hwc(
    const float* __restrict__ x, const float* __restrict__ t,
    float* __restrict__ out, int B)
{
    const int tid = blockIdx.x * 256 + threadIdx.x;
    const int p   = tid >> 2;
    const int cg  = tid & 3;
    if (p >= B) return;

    const float xv0 = x[(size_t)p * 3 + 0];
    const float xv1 = x[(size_t)p * 3 + 1];
    const float xv2 = x[(size_t)p * 3 + 2];
    const float gxs[3] = { xv0, xv0, xv1 };
    const float gys[3] = { xv1, xv2, xv2 };
    float4 acc = make_float4(1.f, 1.f, 1.f, 1.f);

#pragma unroll
    for (int pl = 0; pl < 3; ++pl) {
        const float gx = gxs[pl], gy = gys[pl];
        const float px = (gx + 1.0f) * 0.5f * (float)(R - 1);
        const float py = (gy + 1.0f) * 0.5f * (float)(R - 1);
        const float x0f = floorf(px), y0f = floorf(py);
        const float wx = px - x0f,   wy = py - y0f;
        int x0 = (int)x0f; x0 = min(max(x0, 0), R - 1);
        int y0 = (int)y0f; y0 = min(max(y0, 0), R - 1);
        const int x1 = min(x0 + 1, R - 1);
        const int y1 = min(y0 + 1, R - 1);

        const float* pb = t + (size_t)pl * (size_t)(HW * C) + cg * 4;
        const float4 p00 = *(const float4*)(pb + (size_t)(y0 * R + x0) * C);
        const float4 p01 = *(const float4*)(pb + (size_t)(y0 * R + x1) * C);
        const float4 p10 = *(const float4*)(pb + (size_t)(y1 * R + x0) * C);
        const float4 p11 = *(const float4*)(pb + (size_t)(y1 * R + x1) * C);

        const float w00 = (1.f - wx) * (1.f - wy);
        const float w01 = wx * (1.f - wy);
        const float w10 = (1.f - wx) * wy;
        const float w11 = wx * wy;

        float4 f;
        f.x = p00.x * w00 + p01.x * w01 + p10.x * w10 + p11.x * w11;
        f.y = p00.y * w00 + p01.y * w01 + p10.y * w10 + p11.y * w11;
        f.z = p00.z * w00 + p01.z * w01 + p10.z * w10 + p11.z * w11;
        f.w = p00.w * w00 + p01.w * w01 + p10.w * w10 + p11.w * w11;

        acc.x *= f.x; acc.y *= f.y; acc.z *= f.z; acc.w *= f.w;
    }

    *(float4*)(out + (size_t)p * C + cg * 4) = acc;
}

__global__ __launch_bounds__(256) void sample_chw(
    const float* __restrict__ x,
    const float* __restrict__ p0, const float* __restrict__ p1,
    const float* __restrict__ p2, float* __restrict__ out, int B)
{
    const int tid = blockIdx.x * 256 + threadIdx.x;
    const int p   = tid >> 2;
    const int cg  = tid & 3;
    if (p >= B) return;
    const float xv0 = x[(size_t)p * 3 + 0];
    const float xv1 = x[(size_t)p * 3 + 1];
    const float xv2 = x[(size_t)p * 3 + 2];
    const float gxs[3] = { xv0, xv0, xv1 };
    const float gys[3] = { xv1, xv2, xv2 };
    const float* planes[3] = { p0, p1, p2 };
    float acc[4] = {1.f, 1.f, 1.f, 1.f};
#pragma unroll
    for (int pl = 0; pl < 3; ++pl) {
        const float gx = gxs[pl], gy = gys[pl];
        const float px = (gx + 1.0f) * 0.5f * (float)(R - 1);
        const float py = (gy + 1.0f) * 0.5f * (float)(R - 1);
        const float x0f = floorf(px), y0f = floorf(py);
        const float wx = px - x0f,   wy = py - y0f;
        int x0 = (int)x0f; x0 = min(max(x0, 0), R - 1);
        int y0 = (int)y0f; y0 = min(max(y0, 0), R - 1);
        const int x1 = min(x0 + 1, R - 1);
        const int y1 = min(y0 + 1, R - 1);
        const float w00 = (1.f - wx) * (1.f - wy);
        const float w01 = wx * (1.f - wy);
        const float w10 = (1.f - wx) * wy;
        const float w11 = wx * wy;
        const float* pb = planes[pl];
#pragma unroll
        for (int k = 0; k < 4; ++k) {
            const int c = cg * 4 + k;
            const float* b2 = pb + (size_t)c * HW;
            const float v00 = b2[y0 * R + x0];
            const float v01 = b2[y0 * R + x1];
            const float v10 = b2[y1 * R + x0];
            const float v11 = b2[y1 * R + x1];
            acc[k] *= v00 * w00 + v01 * w01 + v10 * w10 + v11 * w11;
        }
    }
    float* o = out + (size_t)p * C + cg * 4;
    o[0] = acc[0]; o[1] = acc[1]; o[2] = acc[2]; o[3] = acc[3];
}

// ===========================================================================
extern "C" void kernel_launch(void* const* d_in, const int* in_sizes, int n_in,
                              void* d_out, int out_size, void* d_ws, size_t ws_size,
                              hipStream_t stream) {
    const float* x  = (const float*)d_in[0];
    const float* p0 = (const float*)d_in[1];
    const float* p1 = (const float*)d_in[2];
    const float* p2 = (const float*)d_in[3];
    float* out = (float*)d_out;
    const int B = in_sizes[0] / 3;

    const size_t t_bytes    = (size_t)3 * HW * C * sizeof(__half);     // 24 MiB
    const size_t recs_bytes = (size_t)B * 16;                          // 32 MB
    const size_t cnt_bytes  = (size_t)NCNT * 4;                        // 16 KiB
    const size_t off_t      = 0;
    const size_t off_recs   = (t_bytes + 255) & ~(size_t)255;
    const size_t off_counts = (off_recs + recs_bytes + 255) & ~(size_t)255;
    const size_t off_cursor = (off_counts + cnt_bytes + 255) & ~(size_t)255;
    const size_t need_full  = off_cursor + cnt_bytes;

    const size_t need_fp32  = (size_t)3 * HW * C * sizeof(float);      // 48 MiB

    if (d_ws != nullptr && ws_size >= need_full) {
        __half*       t      = (__half*)((char*)d_ws + off_t);
        int4*         recs   = (int4*)((char*)d_ws + off_recs);
        unsigned int* counts = (unsigned int*)((char*)d_ws + off_counts);
        unsigned int* cursor = (unsigned int*)((char*)d_ws + off_cursor);

        dim3 tg(R, R / 64, 3);
        transpose_chw_hwc_h<<<tg, 256, 0, stream>>>(p0, p1, p2, t);

        hipMemsetAsync(counts, 0, cnt_bytes, stream);
        const int nblkP = (B + CHUNK - 1) / CHUNK;
        hist_pts<<<nblkP, 256, 0, stream>>>(x, counts, B);
        scan_counts<<<1, 1024, 0, stream>>>(counts, cursor);
        scatter_pts<<<nblkP, 256, 0, stream>>>(x, cursor, recs, B);

        const int nthr2 = B;                       // 2 lanes/pt, 2 pts/thread
        const int nblk2 = (nthr2 + 255) / 256;
        const int q = nblk2 / 8, r = nblk2 % 8;
        sample_sorted<<<nblk2, 256, 0, stream>>>(recs, t, out, B, q, r);
    } else if (d_ws != nullptr && ws_size >= need_fp32) {
        float* t = (float*)d_ws;
        dim3 tg(R, R / 64, 3);
        transpose_chw_hwc<<<tg, 256, 0, stream>>>(p0, p1, p2, t);
        const int nthr = B * 4;
        const int nblk = (nthr + 255) / 256;
        sample_hwc<<<nblk, 256, 0, stream>>>(x, t, out, B);
    } else {
        const int nthr = B * 4;
        const int nblk = (nthr + 255) / 256;
        sample_chw<<<nblk, 256, 0, stream>>>(x, p0, p1, p2, out, B);
    }
}